// Round 3
// baseline (49617.673 us; speedup 1.0000x reference)
//
#include <hip/hip_runtime.h>
#include <hip/hip_bf16.h>
#include <cstdint>

#define B_ 128
#define T_ 256
#define C_ 512
#define H_ 2048
#define NWG 256
#define NTHR 256
#define NGROUP 8
#define GSIZE 32        // WGs per row-group
#define M_ 16           // batch rows per group
#define FSTRIDE 16      // flag padding (dwords) -> 64 B per flag
#define RSU1 132        // atile row stride in ull: 264 dw == 8 mod 32 -> uniform banks for b128
#define RSS1 528        // row stride in shorts
// DT = (1/(T-1))/N_SUB = 1/765
#define DT_F 0.0013071895424836601f
#define POLL_CAP 8192   // fast-poll iterations before shadow rescue

typedef __bf16 bf16x8 __attribute__((ext_vector_type(8)));
typedef short s16x8 __attribute__((ext_vector_type(8)));
typedef float f32x4 __attribute__((ext_vector_type(4)));
typedef unsigned long long ull;

// ---------------- workspace layout (bytes) ----------------
enum : size_t {
  OFF_FLAGS = 0,                                    // primary flags 8*32*64B = 16 KB
  OFF_SHAD  = 16384,                                // shadow flags (MALL)     16 KB
  OFF_PROBE = 32768,                                // probe tokens            16 KB
  OFF_OK    = 49152,                                // per-WG probe verdict    16 KB
  OFF_W1P   = 65536,
  OFF_W2P = OFF_W1P + (size_t)C_ * H_ * 2,          // 2 MB
  OFF_W3P = OFF_W2P + (size_t)H_ * H_ * 2,          // 8 MB
  OFF_U   = OFF_W3P + (size_t)H_ * C_ * 2,          // 2 MB
  OFF_H1  = OFF_U   + (size_t)NGROUP * M_ * C_ * 2, // 128 KB
  OFF_H2  = OFF_H1  + (size_t)NGROUP * M_ * H_ * 2, // 512 KB
  WS_END  = OFF_H2  + (size_t)NGROUP * M_ * H_ * 2  // ~13.5 MB
};

__device__ __forceinline__ bf16x8 ld_frag(const unsigned short* p) {   // cached (weights)
  s16x8 v = *reinterpret_cast<const s16x8*>(p);
  return __builtin_bit_cast(bf16x8, v);
}
__device__ __forceinline__ bf16x8 lds_frag(const unsigned short* p) {  // ds_read_b128
  s16x8 v = *reinterpret_cast<const s16x8*>(p);
  return __builtin_bit_cast(bf16x8, v);
}
// activation store: fast = plain store (write-through vL1 -> XCD L2, probe-verified);
// slow = agent-scope (MALL), baseline-proven.
__device__ __forceinline__ void st16(unsigned short* p, unsigned short v, bool fast) {
  if (fast) *p = v;
  else __hip_atomic_store(p, v, __ATOMIC_RELAXED, __HIP_MEMORY_SCOPE_AGENT);
}
__device__ __forceinline__ f32x4 mfma16(bf16x8 a, bf16x8 b, f32x4 c) {
  return __builtin_amdgcn_mfma_f32_16x16x32_bf16(a, b, c, 0, 0, 0);
}
__device__ __forceinline__ unsigned short tobf(float f) {
  return __builtin_bit_cast(unsigned short, (__bf16)f);
}
__device__ __forceinline__ float fast_tanh(float v) {
  float e = __expf(2.0f * v);
  return 1.0f - 2.0f / (e + 1.0f);
}
// one L1-bypass (sc0) dword load, drained; used for probe reads and flag polls
__device__ __forceinline__ unsigned ld_sc0_u32(const unsigned* p) {
  unsigned v;
  asm volatile("global_load_dword %0, %1, off sc0\n\t"
               "s_waitcnt vmcnt(0)"
               : "=&v"(v) : "v"(p) : "memory");
  return v;
}
// 8 batched sc0 loads, saddr form (uniform SGPR base + 32-bit voffsets) to keep
// VGPR pressure low; drained inside so outputs are ready for the LDS commit.
__device__ __forceinline__ void issue8f(const ull* base, unsigned o0, unsigned stride, ull v[8]) {
  unsigned a0 = o0,            a1 = o0 + stride,     a2 = o0 + 2 * stride, a3 = o0 + 3 * stride,
           a4 = o0 + 4 * stride, a5 = o0 + 5 * stride, a6 = o0 + 6 * stride, a7 = o0 + 7 * stride;
  asm volatile(
      "global_load_dwordx2 %0, %8, %16 sc0\n\t"
      "global_load_dwordx2 %1, %9, %16 sc0\n\t"
      "global_load_dwordx2 %2, %10, %16 sc0\n\t"
      "global_load_dwordx2 %3, %11, %16 sc0\n\t"
      "global_load_dwordx2 %4, %12, %16 sc0\n\t"
      "global_load_dwordx2 %5, %13, %16 sc0\n\t"
      "global_load_dwordx2 %6, %14, %16 sc0\n\t"
      "global_load_dwordx2 %7, %15, %16 sc0\n\t"
      "s_waitcnt vmcnt(0)"
      : "=&v"(v[0]), "=&v"(v[1]), "=&v"(v[2]), "=&v"(v[3]),
        "=&v"(v[4]), "=&v"(v[5]), "=&v"(v[6]), "=&v"(v[7])
      : "v"(a0), "v"(a1), "v"(a2), "v"(a3), "v"(a4), "v"(a5), "v"(a6), "v"(a7),
        "s"(base)
      : "memory");
}

// ---------------- prologue kernels ----------------
__global__ void init_flags_k(unsigned* f) {
  int i = blockIdx.x * 256 + threadIdx.x;
  if (i < 16384) f[i] = 0u;         // flags + shadow + probe + ok (64 KB)
}

// Pack W[K][N] fp32 -> bf16 in MFMA B-fragment order (validated rounds 1-4):
// packed[((nt*(K/32)+kb)*64 + lane)*8 + j] = W[kb*32 + (lane>>4)*8 + j][nt*16 + (lane&15)]
__global__ void swizzle_w_k(const float* __restrict__ W, unsigned short* __restrict__ Wp,
                            int N, int kblog) {
  int idx = blockIdx.x * 256 + threadIdx.x;
  int j = idx & 7;
  int l = (idx >> 3) & 63;
  int rem = idx >> 9;
  int kb = rem & ((1 << kblog) - 1);
  int nt = rem >> kblog;
  int k = kb * 32 + ((l >> 4) << 3) + j;
  int n = (nt << 4) + (l & 15);
  Wp[idx] = tobf(W[(size_t)k * N + n]);
}

// ---------------- split-phase group barrier (32 WGs) ----------------
// slow: MALL-coherent agent-scope flags (baseline-proven).
// fast: plain flag store (L2) + sc0 polls; every arrive ALSO writes an
// agent-scope shadow flag so a capped poll can always rescue (no hang).
__device__ __forceinline__ void bar_arrive(unsigned* gf, unsigned* gs, int gn,
                                           unsigned gen, bool fast) {
  asm volatile("s_waitcnt vmcnt(0)" ::: "memory");   // own data stores visible
  __syncthreads();                                   // all waves of this WG drained
  if (threadIdx.x == 0) {
    if (fast) {
      gf[gn * FSTRIDE] = gen;                        // plain -> XCD L2
      __hip_atomic_store(&gs[gn * FSTRIDE], gen, __ATOMIC_RELAXED,
                         __HIP_MEMORY_SCOPE_AGENT);  // shadow -> MALL (insurance)
    } else {
      __hip_atomic_store(&gf[gn * FSTRIDE], gen, __ATOMIC_RELAXED,
                         __HIP_MEMORY_SCOPE_AGENT);
    }
  }
}
__device__ __forceinline__ void bar_wait(unsigned* gf, unsigned* gs, unsigned gen,
                                         bool fast, bool& sticky) {
  if (threadIdx.x < GSIZE) {
    const unsigned* fp = gf + threadIdx.x * FSTRIDE;
    const unsigned* sp = gs + threadIdx.x * FSTRIDE;
    if (fast && !sticky) {
      int it = 0; bool done = false;
      for (;;) {
        if (ld_sc0_u32(fp) >= gen) { done = true; break; }
        if (++it > POLL_CAP) break;
        __builtin_amdgcn_s_sleep(1);
      }
      if (!done) {                                   // shadow rescue (never hangs)
        while (__hip_atomic_load(sp, __ATOMIC_RELAXED, __HIP_MEMORY_SCOPE_AGENT) < gen)
          __builtin_amdgcn_s_sleep(2);
        if (ld_sc0_u32(fp) < gen) sticky = true;     // fast flags demonstrably broken
      }
    } else if (fast) {
      while (__hip_atomic_load(sp, __ATOMIC_RELAXED, __HIP_MEMORY_SCOPE_AGENT) < gen)
        __builtin_amdgcn_s_sleep(1);
    } else {
      while (__hip_atomic_load(fp, __ATOMIC_RELAXED, __HIP_MEMORY_SCOPE_AGENT) < gen)
        __builtin_amdgcn_s_sleep(1);
    }
  }
  __syncthreads();
}

// ---------------- staging: batched loads + deferred LDS commit ----------------
// chunk = 16 rows x 128 ull; 256 threads x 8 ull each.
// fast: sc0 loads (L1 bypass -> XCD L2 hit); slow: agent-scope (MALL), baseline.
__device__ __forceinline__ void issue_u(const ull* __restrict__ g, int tid, ull v[8], bool fast) {
  if (fast) {
    issue8f(g, (unsigned)(tid * 8), 2048u, v);       // addr_j bytes = tid*8 + j*2048
  } else {
    #pragma unroll
    for (int j = 0; j < 8; ++j)
      v[j] = __hip_atomic_load(g + j * NTHR + tid, __ATOMIC_RELAXED, __HIP_MEMORY_SCOPE_AGENT);
  }
}
__device__ __forceinline__ void issue_c(const ull* __restrict__ g, int tid, ull v[8], bool fast) {
  if (fast) {
    unsigned o0 = (unsigned)((((tid >> 7) * 512) + (tid & 127)) * 8);
    issue8f(g, o0, 8192u, v);                        // addr_j bytes = o0 + j*8192
  } else {
    #pragma unroll
    for (int j = 0; j < 8; ++j) {
      int i = j * NTHR + tid;
      v[j] = __hip_atomic_load(g + (size_t)(i >> 7) * 512 + (i & 127),
                               __ATOMIC_RELAXED, __HIP_MEMORY_SCOPE_AGENT);
    }
  }
}
__device__ __forceinline__ void commit(ull* __restrict__ lds, int tid, const ull v[8]) {
  #pragma unroll
  for (int j = 0; j < 8; ++j) {
    int i = j * NTHR + tid;
    lds[(i >> 7) * RSU1 + (i & 127)] = v[j];
  }
}

// compile-time-indexed compute macros (keep w2r/w3r register-resident!)
#define L2CHUNK(c, buf) {                                                     \
  const unsigned short* al = (const unsigned short*)atile[buf] + llo * RSS1 + lhi * 8; \
  _Pragma("unroll")                                                           \
  for (int jj = 0; jj < 8; ++jj) {                                            \
    acc0 = mfma16(lds_frag(al + (2 * jj) * 32),     w2r[(c) * 16 + 2 * jj],     acc0); \
    acc1 = mfma16(lds_frag(al + (2 * jj + 1) * 32), w2r[(c) * 16 + 2 * jj + 1], acc1); \
  } }

#define L3CHUNK(c, buf) {                                                     \
  const unsigned short* al = (const unsigned short*)atile[buf] + llo * RSS1 + lhi * 8; \
  _Pragma("unroll")                                                           \
  for (int jj = 0; jj < 2; ++jj) {                                            \
    acc0 = mfma16(lds_frag(al + (wave * 4 + 2 * jj) * 32),     w3r[(c) * 4 + 2 * jj],     acc0); \
    acc1 = mfma16(lds_frag(al + (wave * 4 + 2 * jj + 1) * 32), w3r[(c) * 4 + 2 * jj + 1], acc1); \
  } }

// ---------------- persistent ODE kernel ----------------
// 8 groups x 32 WGs, g = wg&7 (round-robin dispatch => one group per XCD).
// Fast (L2-scope) mode is enabled ONLY if a proof-of-communication probe passes:
// each WG plain-stores a unique token; after the agent-scope barrier every WG
// sc0-reads all 32 tokens. All-match proves plain-store -> shared-L2 -> sc0-load
// visibility (i.e. same XCD + write-through L1). All decision traffic is
// agent-scope; the probe has no unproven polling => cannot hang. Probe fail =>
// exact baseline behavior.
__global__ __launch_bounds__(NTHR, 1) void ode_persist_k(
    const float* __restrict__ x, const float* __restrict__ b1,
    const float* __restrict__ b2, const float* __restrict__ b3,
    float* __restrict__ out, unsigned char* __restrict__ ws) {
  const int wg = blockIdx.x, tid = threadIdx.x;
  const int g = wg & 7, gn = wg >> 3;
  const int wave = tid >> 6, lane = tid & 63;
  const int lhi = lane >> 4, llo = lane & 15;

  unsigned* gflags = (unsigned*)(ws + OFF_FLAGS) + g * GSIZE * FSTRIDE;
  unsigned* gshad  = (unsigned*)(ws + OFF_SHAD)  + g * GSIZE * FSTRIDE;
  unsigned* probe  = (unsigned*)(ws + OFF_PROBE) + g * GSIZE * FSTRIDE;
  unsigned* okarr  = (unsigned*)(ws + OFF_OK)    + g * GSIZE * FSTRIDE;
  const unsigned short* W1p = (const unsigned short*)(ws + OFF_W1P);
  const unsigned short* W2p = (const unsigned short*)(ws + OFF_W2P);
  const unsigned short* W3p = (const unsigned short*)(ws + OFF_W3P);
  const ull* ubuf_u = (const ull*)(ws + OFF_U)  + (size_t)g * (M_ * C_ / 4);
  const ull* h1_u   = (const ull*)(ws + OFF_H1) + (size_t)g * (M_ * H_ / 4);
  const ull* h2_u   = (const ull*)(ws + OFF_H2) + (size_t)g * (M_ * H_ / 4);
  unsigned short* ubuf_s = (unsigned short*)(ws + OFF_U)  + (size_t)g * M_ * C_;
  unsigned short* h1_s   = (unsigned short*)(ws + OFF_H1) + (size_t)g * M_ * H_;
  unsigned short* h2_s   = (unsigned short*)(ws + OFF_H2) + (size_t)g * M_ * H_;

  __shared__ alignas(16) ull atile[2][M_ * RSU1];   // 2 x 16.5 KB
  __shared__ float red[4][256];
  __shared__ float ytile[256], k1t[256], k2t[256], k3t[256];
  __shared__ int sh_ok;

  // weight bases (B-fragment layout)
  const int n16 = gn * 4 + wave;                    // layers 1,2 column tile
  const unsigned short* bp1 = W1p + (size_t)n16 * 16 * 512 + lane * 8;
  const unsigned short* bp2 = W2p + (size_t)n16 * 64 * 512 + lane * 8;
  const unsigned short* bp3 = W3p + (size_t)gn  * 64 * 512 + lane * 8;

  // ---- register-resident W2 (256 VGPR) and W3 (64 VGPR) slices ----
  bf16x8 w2r[64], w3r[16];
  #pragma unroll
  for (int kb = 0; kb < 64; ++kb) w2r[kb] = ld_frag(bp2 + kb * 512);
  #pragma unroll
  for (int q = 0; q < 16; ++q)    // q = c*4+jj -> global kb = c*16 + wave*4 + jj
    w3r[q] = ld_frag(bp3 + ((q >> 2) * 16 + wave * 4 + (q & 3)) * 512);

  // biases: fixed per lane -> hoist to registers
  const float bb1 = b1[n16 * 16 + llo];
  const float bb2 = b2[n16 * 16 + llo];
  const float bb3 = b3[gn * 16 + llo];

  // ---- init: y tile from x, out[:,0,:], ubuf = bf16(y); plain probe token ----
  {
    int row = tid >> 4, c16 = tid & 15;
    int col = gn * 16 + c16;
    int b = g * M_ + row;
    float v = x[(size_t)b * (T_ * C_) + col];
    ytile[tid] = v;
    out[(size_t)b * (T_ * C_) + col] = v;
    __hip_atomic_store(&ubuf_s[row * C_ + col], tobf(v),
                       __ATOMIC_RELAXED, __HIP_MEMORY_SCOPE_AGENT);
  }
  if (tid == 0) sh_ok = 1;
  if (tid == 1) probe[gn * FSTRIDE] = 0xA5A50000u | (unsigned)(g << 8) | (unsigned)gn;
  unsigned gen = 0;
  bool sticky = false;
  bar_arrive(gflags, gshad, gn, ++gen, false);       // gen 1: agent-scope (proven)
  bar_wait(gflags, gshad, gen, false, sticky);

  // ---- probe read: can we see every member's PLAIN store via sc0? ----
  {
    bool myok = true;
    if (tid < GSIZE) {
      unsigned v = ld_sc0_u32(&probe[tid * FSTRIDE]);
      myok = (v == (0xA5A50000u | (unsigned)(g << 8) | (unsigned)tid));
    }
    __syncthreads();                                 // sh_ok=1 visible
    if (!myok) sh_ok = 0;                            // benign same-value race
    __syncthreads();
    if (tid == 0)
      __hip_atomic_store(&okarr[gn * FSTRIDE], sh_ok ? 2u : 1u,
                         __ATOMIC_RELAXED, __HIP_MEMORY_SCOPE_AGENT);
  }
  bar_arrive(gflags, gshad, gn, ++gen, false);       // gen 2: agent-scope
  bar_wait(gflags, gshad, gen, false, sticky);
  {
    bool myok = true;
    if (tid < GSIZE)
      myok = (__hip_atomic_load(&okarr[tid * FSTRIDE], __ATOMIC_RELAXED,
                                __HIP_MEMORY_SCOPE_AGENT) == 2u);
    __syncthreads();
    if (!myok) sh_ok = 0;
    __syncthreads();
  }
  const bool fast = sh_ok != 0;                      // uniform across WG & group

  ull va[8], vb[8];
  #pragma unroll 1
  for (int t = 0; t < T_ - 1; ++t) {
    #pragma unroll 1
    for (int sub = 0; sub < 3; ++sub) {
      #pragma unroll 1
      for (int st = 0; st < 4; ++st) {
        // ================= layer 1: [16x512]@[512x2048], tanh =================
        {
          issue_u(ubuf_u, tid, va, fast);
          bf16x8 w1f[16];                       // W1 streamed: L1/L2-cached
          #pragma unroll
          for (int kb = 0; kb < 16; ++kb) w1f[kb] = ld_frag(bp1 + kb * 512);
          commit(atile[0], tid, va);
          __syncthreads();
          f32x4 acc0 = {0.f, 0.f, 0.f, 0.f}, acc1 = {0.f, 0.f, 0.f, 0.f};
          const unsigned short* al = (const unsigned short*)atile[0] + llo * RSS1 + lhi * 8;
          #pragma unroll
          for (int jj = 0; jj < 8; ++jj) {
            acc0 = mfma16(lds_frag(al + (2 * jj) * 32),     w1f[2 * jj],     acc0);
            acc1 = mfma16(lds_frag(al + (2 * jj + 1) * 32), w1f[2 * jj + 1], acc1);
          }
          f32x4 a = acc0 + acc1;
          const int col = n16 * 16 + llo;
          #pragma unroll
          for (int r = 0; r < 4; ++r)
            st16(&h1_s[(lhi * 4 + r) * H_ + col], tobf(fast_tanh(a[r] + bb1)), fast);
        }
        bar_arrive(gflags, gshad, gn, ++gen, fast);
        bar_wait(gflags, gshad, gen, fast, sticky);

        // ========== layer 2: [16x2048]@[2048x2048], tanh, weights in VGPRs ==========
        {
          f32x4 acc0 = {0.f, 0.f, 0.f, 0.f}, acc1 = {0.f, 0.f, 0.f, 0.f};
          issue_c(h1_u,       tid, va, fast);
          issue_c(h1_u + 128, tid, vb, fast);    // 2-deep staging pipeline
          commit(atile[0], tid, va);
          __syncthreads();
          issue_c(h1_u + 256, tid, va, fast);
          L2CHUNK(0, 0);
          commit(atile[1], tid, vb);
          __syncthreads();
          issue_c(h1_u + 384, tid, vb, fast);
          L2CHUNK(1, 1);
          commit(atile[0], tid, va);
          __syncthreads();
          L2CHUNK(2, 0);
          commit(atile[1], tid, vb);
          __syncthreads();
          L2CHUNK(3, 1);
          f32x4 a = acc0 + acc1;
          const int col = n16 * 16 + llo;
          #pragma unroll
          for (int r = 0; r < 4; ++r)
            st16(&h2_s[(lhi * 4 + r) * H_ + col], tobf(fast_tanh(a[r] + bb2)), fast);
        }
        bar_arrive(gflags, gshad, gn, ++gen, fast);
        bar_wait(gflags, gshad, gen, fast, sticky);

        // ==== layer 3: [16x2048]@[2048x512], wave K-split, weights in VGPRs, RK4 ====
        {
          f32x4 acc0 = {0.f, 0.f, 0.f, 0.f}, acc1 = {0.f, 0.f, 0.f, 0.f};
          issue_c(h2_u,       tid, va, fast);
          issue_c(h2_u + 128, tid, vb, fast);
          commit(atile[0], tid, va);
          __syncthreads();
          issue_c(h2_u + 256, tid, va, fast);
          L3CHUNK(0, 0);
          commit(atile[1], tid, vb);
          __syncthreads();
          issue_c(h2_u + 384, tid, vb, fast);
          L3CHUNK(1, 1);
          commit(atile[0], tid, va);
          __syncthreads();
          L3CHUNK(2, 0);
          commit(atile[1], tid, vb);
          __syncthreads();
          L3CHUNK(3, 1);
          f32x4 a = acc0 + acc1;
          #pragma unroll
          for (int r = 0; r < 4; ++r) red[wave][(lhi * 4 + r) * 16 + llo] = a[r];
          __syncthreads();
          if (wave == 0) {
            const float dt = DT_F;
            #pragma unroll
            for (int r = 0; r < 4; ++r) {
              int row = lhi * 4 + r;
              int i = row * 16 + llo;
              float z = red[0][i] + red[1][i] + red[2][i] + red[3][i] + bb3;
              float yv = ytile[i];
              unsigned short* up = &ubuf_s[row * C_ + gn * 16 + llo];
              if (st == 0)      { k1t[i] = z; st16(up, tobf(yv + 0.5f * dt * z), fast); }
              else if (st == 1) { k2t[i] = z; st16(up, tobf(yv + 0.5f * dt * z), fast); }
              else if (st == 2) { k3t[i] = z; st16(up, tobf(yv + dt * z), fast); }
              else {
                float yn = yv + (dt * (1.0f / 6.0f)) * (k1t[i] + 2.f * k2t[i] + 2.f * k3t[i] + z);
                ytile[i] = yn;
                st16(up, tobf(yn), fast);
                if (sub == 2)
                  out[(size_t)(g * M_ + row) * (T_ * C_) + (size_t)(t + 1) * C_ + gn * 16 + llo] = yn;
              }
            }
          }
        }
        bar_arrive(gflags, gshad, gn, ++gen, fast);
        bar_wait(gflags, gshad, gen, fast, sticky);
      }
    }
  }
}

// ---------------- host ----------------
extern "C" void kernel_launch(void* const* d_in, const int* in_sizes, int n_in,
                              void* d_out, int out_size, void* d_ws, size_t ws_size,
                              hipStream_t stream) {
  (void)in_sizes; (void)n_in; (void)out_size; (void)ws_size;
  const float* x  = (const float*)d_in[0];
  const float* W1 = (const float*)d_in[1];
  const float* b1 = (const float*)d_in[2];
  const float* W2 = (const float*)d_in[3];
  const float* b2 = (const float*)d_in[4];
  const float* W3 = (const float*)d_in[5];
  const float* b3 = (const float*)d_in[6];
  float* out = (float*)d_out;
  unsigned char* ws = (unsigned char*)d_ws;

  init_flags_k<<<64, 256, 0, stream>>>((unsigned*)(ws + OFF_FLAGS));
  // W1: K=512 (kblog=4), N=2048 ; W2: K=2048 (kblog=6), N=2048 ; W3: K=2048 (kblog=6), N=512
  swizzle_w_k<<<(C_ * H_) / 256, 256, 0, stream>>>(W1, (unsigned short*)(ws + OFF_W1P), H_, 4);
  swizzle_w_k<<<(H_ * H_) / 256, 256, 0, stream>>>(W2, (unsigned short*)(ws + OFF_W2P), H_, 6);
  swizzle_w_k<<<(H_ * C_) / 256, 256, 0, stream>>>(W3, (unsigned short*)(ws + OFF_W3P), C_, 6);

  ode_persist_k<<<NWG, NTHR, 0, stream>>>(x, b1, b2, b3, out, ws);
}